// Round 7
// baseline (307.157 us; speedup 1.0000x reference)
//
#include <hip/hip_runtime.h>

// VanillaRNN: B=4096, T=1024, I=3, H=32, O=2
// out[b,t,j] = h_t[j];  h_t = tanh(x_t @ W_ih^T + b_ih + b_hh + h_{t-1} @ W_hh^T)
// h_n[b,o] = h_T @ W_fc^T + b_fc
//
// R6: one batch across a SPLIT 32-lane set: lanes [16q..16q+15] u [32+16q..+15].
// Lane owns one output j = p + 16*hi (p=lane&15, hi=lane>=32, q=(lane>>4)&1).
// Cross-half h exchange = ONE v_permlane32_swap_b32 (VALU, not LDS pipe):
//   r = permlane32_swap(h,h) -> r.x = H[p] (low half), r.y = H[p+16] (high)
//   valid in EVERY lane, no select needed.
// Then 15 independent dpp row_ror:m pair-rotations + 16 v_pk_fma_f32 with W
// pre-permuted by q=(p-m)&15 (indexing convention verified in R4b/R5).
// 2 batches/wave -> 2048 waves = 2 waves/SIMD: second wave fills dep bubbles.
// DEPTH=4 + nontemporal stores (R4b-proven). W pre-scaled by 2*log2(e).

typedef float f2  __attribute__((ext_vector_type(2)));
typedef int   i2v __attribute__((ext_vector_type(2)));

#define RNN_B 4096
#define RNN_T 1024
#define RNN_H 32
#define GROUPS 8              // batches per block (4 waves x 2 batches)
#define BLOCK 256
#define DEPTH 4               // T-unroll / x prefetch distance

#define SCALE 2.8853900817779268f   // 2*log2(e)

template <int M>
__device__ __forceinline__ f2 rotm(f2 v) {
    // DPP row_ror:M — lane i reads lane (i-M)&15 within its 16-lane row
    f2 r;
    r.x = __int_as_float(__builtin_amdgcn_mov_dpp(__float_as_int(v.x), 0x120 | M, 0xf, 0xf, true));
    r.y = __int_as_float(__builtin_amdgcn_mov_dpp(__float_as_int(v.y), 0x120 | M, 0xf, 0xf, true));
    return r;
}

__global__ __launch_bounds__(BLOCK) void vanilla_rnn_kernel(
    const float* __restrict__ x,     // [B,T,3]
    const float* __restrict__ W_ih,  // [32,3]
    const float* __restrict__ b_ih,  // [32]
    const float* __restrict__ W_hh,  // [32,32]
    const float* __restrict__ b_hh,  // [32]
    const float* __restrict__ W_fc,  // [2,32]
    const float* __restrict__ b_fc,  // [2]
    float* __restrict__ out,         // [B,T,32]
    float* __restrict__ hn_out)      // [B,2]
{
    const int tid  = threadIdx.x;
    const int w    = tid >> 6;         // wave within block
    const int lane = tid & 63;
    const int p    = lane & 15;        // position within 16-row
    const int q    = (lane >> 4) & 1;  // batch within wave
    const int hi   = lane >> 5;        // 0: owns j=p, 1: owns j=p+16
    const int j    = p + 16 * hi;
    const int b    = blockIdx.x * GROUPS + w * 2 + q;

    __shared__ float hs[GROUPS][32];   // epilogue only
    const int gg = w * 2 + q;

    // W_hh row j in rotation order, paired (low-half k, high-half k), scaled.
    // After pair-rotation by m, hp2 holds {H[(p-m)&15], H[((p-m)&15)+16]}.
    f2 Wp[16];
#pragma unroll
    for (int m = 0; m < 16; ++m) {
        const int qq = (p - m) & 15;
        Wp[m].x = W_hh[j * 32 + qq]      * SCALE;
        Wp[m].y = W_hh[j * 32 + 16 + qq] * SCALE;
    }

    const float wi0 = W_ih[j * 3 + 0] * SCALE;
    const float wi1 = W_ih[j * 3 + 1] * SCALE;
    const float wi2 = W_ih[j * 3 + 2] * SCALE;
    const float bs  = (b_ih[j] + b_hh[j]) * SCALE;

    const float* xb = x + (size_t)b * RNN_T * 3;
    float*       ob = out + (size_t)b * RNN_T * RNN_H;

    float xs[DEPTH][3];
#pragma unroll
    for (int d = 0; d < DEPTH; ++d)
#pragma unroll
        for (int c = 0; c < 3; ++c) xs[d][c] = xb[d * 3 + c];

    float hj = 0.0f;                   // own H[j]

    for (int tb = 0; tb < RNN_T; tb += DEPTH) {
        const int tnb = (tb + DEPTH < RNN_T) ? (tb + DEPTH) : tb;
        float nxs[DEPTH][3];
#pragma unroll
        for (int d = 0; d < DEPTH; ++d)
#pragma unroll
            for (int c = 0; c < 3; ++c) nxs[d][c] = xb[(tnb + d) * 3 + c];

        // pre-scaled x-projection for this block (h-independent)
        float xp[DEPTH];
#pragma unroll
        for (int d = 0; d < DEPTH; ++d) {
            float v = fmaf(wi0, xs[d][0], bs);
            v = fmaf(wi1, xs[d][1], v);
            v = fmaf(wi2, xs[d][2], v);
            xp[d] = v;
        }

#pragma unroll
        for (int d = 0; d < DEPTH; ++d) {
            // both halves' h, p-aligned, in every lane (pure VALU)
            const i2v r = __builtin_amdgcn_permlane32_swap(
                __float_as_int(hj), __float_as_int(hj), false, false);
            f2 hp2;
            hp2.x = __int_as_float(r.x);   // H[p]      (low half)
            hp2.y = __int_as_float(r.y);   // H[p+16]   (high half)

            // 2 independent 8-deep pk_fma chains
            f2 a0, a1;
            a0.x = xp[d]; a0.y = 0.0f;
            a1.x = 0.0f;  a1.y = 0.0f;

            a0 = __builtin_elementwise_fma(hp2, Wp[0], a0);
#define ROT_STEP(M, AA)                                            \
            {                                                      \
                const f2 rr = rotm<M>(hp2);                        \
                AA = __builtin_elementwise_fma(rr, Wp[M], AA);     \
            }
            ROT_STEP(1,  a1)  ROT_STEP(2,  a0)
            ROT_STEP(3,  a1)  ROT_STEP(4,  a0)
            ROT_STEP(5,  a1)  ROT_STEP(6,  a0)
            ROT_STEP(7,  a1)  ROT_STEP(8,  a0)
            ROT_STEP(9,  a1)  ROT_STEP(10, a0)
            ROT_STEP(11, a1)  ROT_STEP(12, a0)
            ROT_STEP(13, a1)  ROT_STEP(14, a0)
            ROT_STEP(15, a1)
#undef ROT_STEP

            const f2 s = a0 + a1;
            const float y = s.x + s.y;     // = 2*log2e * (pre-tanh)

            // tanh(z) = 1 - 2/(exp2(2*log2e*z)+1); inf-safe
            const float e  = exp2f(y);
            const float th = fmaf(-2.0f, __builtin_amdgcn_rcpf(e + 1.0f), 1.0f);

            __builtin_nontemporal_store(th, &ob[(size_t)(tb + d) * RNN_H + j]);
            hj = th;
        }

#pragma unroll
        for (int d = 0; d < DEPTH; ++d)
#pragma unroll
            for (int c = 0; c < 3; ++c) xs[d][c] = nxs[d][c];
    }

    // h_n = h_T @ W_fc^T + b_fc  (all lanes of this batch are in this wave)
    hs[gg][j] = hj;
    if (hi == 0 && p < 2) {
        float acc = b_fc[p];
#pragma unroll
        for (int k = 0; k < 32; ++k) acc = fmaf(W_fc[p * 32 + k], hs[gg][k], acc);
        hn_out[(size_t)b * 2 + p] = acc;
    }
}

extern "C" void kernel_launch(void* const* d_in, const int* in_sizes, int n_in,
                              void* d_out, int out_size, void* d_ws, size_t ws_size,
                              hipStream_t stream) {
    const float* x    = (const float*)d_in[0];
    const float* W_ih = (const float*)d_in[1];
    const float* b_ih = (const float*)d_in[2];
    const float* W_hh = (const float*)d_in[3];
    const float* b_hh = (const float*)d_in[4];
    const float* W_fc = (const float*)d_in[5];
    const float* b_fc = (const float*)d_in[6];

    float* out    = (float*)d_out;                                   // [B,T,H]
    float* hn_out = out + (size_t)RNN_B * RNN_T * RNN_H;             // [B,2]

    const int grid = RNN_B / GROUPS;  // 512 blocks, 2048 waves = 2/SIMD
    vanilla_rnn_kernel<<<grid, BLOCK, 0, stream>>>(
        x, W_ih, b_ih, W_hh, b_hh, W_fc, b_fc, out, hn_out);
}

// Round 8
// 257.935 us; speedup vs baseline: 1.1908x; 1.1908x over previous
//
#include <hip/hip_runtime.h>

// VanillaRNN: B=4096, T=1024, I=3, H=32, O=2
// out[b,t,j] = h_t[j];  h_t = tanh(x_t @ W_ih^T + b_ih + b_hh + h_{t-1} @ W_hh^T)
// h_n[b,o] = h_T @ W_fc^T + b_fc
//
// R7 = R4b math/layout (16 lanes/batch, lane owns j=2p,2p+1, independent dpp
// row_ror:m pair rotations, W pre-scaled by 2*log2e, 1 wave/SIMD) with the
// store-register-reuse stall removed:
//  - outputs staged in a double-buffered register ring (oring0/oring1);
//    all DEPTH stores issued at block end; a ring register is redefined
//    TWO blocks (~8 steps) later -> store retirement never on the h-chain
//  - x prefetch also double-buffered (xr0/xr1), distance 2 blocks
//  - plain cached stores (ack at L2, write-back off critical path)
//  - main loop + no-prefetch tail (no index clamping)

typedef float f2 __attribute__((ext_vector_type(2)));

#define RNN_B 4096
#define RNN_T 1024
#define RNN_H 32
#define GROUPS 16             // batches per block (16-lane groups)
#define BLOCK 256
#define DEPTH 4               // steps per block; ring reuse distance = 2*DEPTH

#define SCALE 2.8853900817779268f   // 2*log2(e)

template <int M>
__device__ __forceinline__ f2 rotm(f2 v) {
    // DPP row_ror:M — lane i reads lane (i-M)&15 within its 16-lane row
    f2 r;
    r.x = __int_as_float(__builtin_amdgcn_mov_dpp(__float_as_int(v.x), 0x120 | M, 0xf, 0xf, true));
    r.y = __int_as_float(__builtin_amdgcn_mov_dpp(__float_as_int(v.y), 0x120 | M, 0xf, 0xf, true));
    return r;
}

template <bool PF>
__device__ __forceinline__ void rnn_block(
    int tb, const float* __restrict__ xb, float* __restrict__ ob, int p,
    float (&xr)[DEPTH][3], f2 (&oring)[DEPTH], float& hj0, float& hj1,
    const f2 (&Wa)[16], const f2 (&Wb)[16],
    const f2 wi0, const f2 wi1, const f2 wi2, const f2 bs)
{
    // x-projection for this block (consumes xr before it is overwritten)
    f2 xp[DEPTH];
#pragma unroll
    for (int d = 0; d < DEPTH; ++d) {
        f2 v = bs;
        v = __builtin_elementwise_fma(wi0, (f2){xr[d][0], xr[d][0]}, v);
        v = __builtin_elementwise_fma(wi1, (f2){xr[d][1], xr[d][1]}, v);
        v = __builtin_elementwise_fma(wi2, (f2){xr[d][2], xr[d][2]}, v);
        xp[d] = v;
    }

    // prefetch x for block tb+2*DEPTH into xr (consumed 2 blocks from now)
    if (PF) {
#pragma unroll
        for (int d = 0; d < DEPTH; ++d)
#pragma unroll
            for (int c = 0; c < 3; ++c)
                xr[d][c] = xb[(tb + 2 * DEPTH + d) * 3 + c];
    }

#pragma unroll
    for (int d = 0; d < DEPTH; ++d) {
        f2 hp; hp.x = hj0; hp.y = hj1;

        f2 acc_a, acc_b;
        acc_a.x = xp[d].x; acc_a.y = 0.0f;
        acc_b.x = xp[d].y; acc_b.y = 0.0f;

        acc_a = __builtin_elementwise_fma(hp, Wa[0], acc_a);
        acc_b = __builtin_elementwise_fma(hp, Wb[0], acc_b);
#define ROT_STEP(M)                                               \
        {                                                         \
            const f2 r = rotm<M>(hp);                             \
            acc_a = __builtin_elementwise_fma(r, Wa[M], acc_a);   \
            acc_b = __builtin_elementwise_fma(r, Wb[M], acc_b);   \
        }
        ROT_STEP(1)  ROT_STEP(2)  ROT_STEP(3)  ROT_STEP(4)
        ROT_STEP(5)  ROT_STEP(6)  ROT_STEP(7)  ROT_STEP(8)
        ROT_STEP(9)  ROT_STEP(10) ROT_STEP(11) ROT_STEP(12)
        ROT_STEP(13) ROT_STEP(14) ROT_STEP(15)
#undef ROT_STEP

        const float ya = acc_a.x + acc_a.y;   // = 2*log2e * (pre-tanh)
        const float yb = acc_b.x + acc_b.y;

        // tanh(z) = 1 - 2/(exp2(2*log2e*z)+1); inf-safe
        const float ea = exp2f(ya);
        const float eb = exp2f(yb);
        const float tha = fmaf(-2.0f, __builtin_amdgcn_rcpf(ea + 1.0f), 1.0f);
        const float thb = fmaf(-2.0f, __builtin_amdgcn_rcpf(eb + 1.0f), 1.0f);

        oring[d].x = tha; oring[d].y = thb;
        hj0 = tha; hj1 = thb;
    }

    // grouped stores; oring regs not redefined for another 2*DEPTH steps
#pragma unroll
    for (int d = 0; d < DEPTH; ++d)
        *(reinterpret_cast<f2*>(ob + (size_t)(tb + d) * RNN_H) + p) = oring[d];
}

__global__ __launch_bounds__(BLOCK) void vanilla_rnn_kernel(
    const float* __restrict__ x,     // [B,T,3]
    const float* __restrict__ W_ih,  // [32,3]
    const float* __restrict__ b_ih,  // [32]
    const float* __restrict__ W_hh,  // [32,32]
    const float* __restrict__ b_hh,  // [32]
    const float* __restrict__ W_fc,  // [2,32]
    const float* __restrict__ b_fc,  // [2]
    float* __restrict__ out,         // [B,T,32]
    float* __restrict__ hn_out)      // [B,2]
{
    const int tid = threadIdx.x;
    const int g   = tid >> 4;        // batch group within block
    const int p   = tid & 15;        // pair position within 16-lane row
    const int b   = blockIdx.x * GROUPS + g;
    const int j0  = 2 * p;
    const int j1  = 2 * p + 1;

    __shared__ float hs[GROUPS][32]; // epilogue only

    // W_hh rows j0,j1 in rotation order (pair q=(p-m)&15), pre-scaled.
    f2 Wa[16], Wb[16];
#pragma unroll
    for (int m = 0; m < 16; ++m) {
        const int q = (p - m) & 15;
        Wa[m].x = W_hh[j0 * 32 + 2 * q]     * SCALE;
        Wa[m].y = W_hh[j0 * 32 + 2 * q + 1] * SCALE;
        Wb[m].x = W_hh[j1 * 32 + 2 * q]     * SCALE;
        Wb[m].y = W_hh[j1 * 32 + 2 * q + 1] * SCALE;
    }

    // x-projection constants (.x -> j0, .y -> j1)
    f2 wi0, wi1, wi2, bs;
    wi0.x = W_ih[j0 * 3 + 0] * SCALE;  wi0.y = W_ih[j1 * 3 + 0] * SCALE;
    wi1.x = W_ih[j0 * 3 + 1] * SCALE;  wi1.y = W_ih[j1 * 3 + 1] * SCALE;
    wi2.x = W_ih[j0 * 3 + 2] * SCALE;  wi2.y = W_ih[j1 * 3 + 2] * SCALE;
    bs.x  = (b_ih[j0] + b_hh[j0]) * SCALE;
    bs.y  = (b_ih[j1] + b_hh[j1]) * SCALE;

    const float* xb = x + (size_t)b * RNN_T * 3;
    float*       ob = out + (size_t)b * RNN_T * RNN_H;

    // double-buffered x prefetch and output rings
    float xr0[DEPTH][3], xr1[DEPTH][3];
#pragma unroll
    for (int d = 0; d < DEPTH; ++d)
#pragma unroll
        for (int c = 0; c < 3; ++c) {
            xr0[d][c] = xb[d * 3 + c];
            xr1[d][c] = xb[(DEPTH + d) * 3 + c];
        }
    f2 oring0[DEPTH], oring1[DEPTH];

    float hj0 = 0.0f, hj1 = 0.0f;

    int tb2 = 0;
    for (; tb2 < RNN_T - 2 * DEPTH; tb2 += 2 * DEPTH) {
        rnn_block<true>(tb2,         xb, ob, p, xr0, oring0, hj0, hj1, Wa, Wb, wi0, wi1, wi2, bs);
        rnn_block<true>(tb2 + DEPTH, xb, ob, p, xr1, oring1, hj0, hj1, Wa, Wb, wi0, wi1, wi2, bs);
    }
    rnn_block<false>(tb2,         xb, ob, p, xr0, oring0, hj0, hj1, Wa, Wb, wi0, wi1, wi2, bs);
    rnn_block<false>(tb2 + DEPTH, xb, ob, p, xr1, oring1, hj0, hj1, Wa, Wb, wi0, wi1, wi2, bs);

    // h_n = h_T @ W_fc^T + b_fc  (16-lane group is wave-internal, no barrier)
    hs[g][j0] = hj0;
    hs[g][j1] = hj1;
    if (p < 2) {
        float acc = b_fc[p];
#pragma unroll
        for (int k = 0; k < 32; ++k) acc = fmaf(W_fc[p * 32 + k], hs[g][k], acc);
        hn_out[(size_t)b * 2 + p] = acc;
    }
}

extern "C" void kernel_launch(void* const* d_in, const int* in_sizes, int n_in,
                              void* d_out, int out_size, void* d_ws, size_t ws_size,
                              hipStream_t stream) {
    const float* x    = (const float*)d_in[0];
    const float* W_ih = (const float*)d_in[1];
    const float* b_ih = (const float*)d_in[2];
    const float* W_hh = (const float*)d_in[3];
    const float* b_hh = (const float*)d_in[4];
    const float* W_fc = (const float*)d_in[5];
    const float* b_fc = (const float*)d_in[6];

    float* out    = (float*)d_out;                                   // [B,T,H]
    float* hn_out = out + (size_t)RNN_B * RNN_T * RNN_H;             // [B,2]

    const int grid = RNN_B / GROUPS;  // 256 blocks = 1024 waves = 1/SIMD
    vanilla_rnn_kernel<<<grid, BLOCK, 0, stream>>>(
        x, W_ih, b_ih, W_hh, b_hh, W_fc, b_fc, out, hn_out);
}

// Round 9
// 231.925 us; speedup vs baseline: 1.3244x; 1.1121x over previous
//
#include <hip/hip_runtime.h>

// VanillaRNN: B=4096, T=1024, I=3, H=32, O=2
// out[b,t,j] = h_t[j];  h_t = tanh(x_t @ W_ih^T + b_ih + b_hh + h_{t-1} @ W_hh^T)
// h_n[b,o] = h_T @ W_fc^T + b_fc
//
// R8 = exact R4b (best: 224us; 16 lanes/batch, lane owns j=2p,2p+1,
// independent dpp row_ror:m pair rotations, DEPTH=4, nontemporal stores,
// 1 wave/SIMD) with ONE change: tanh tail = clamped Pade(7,6) rational,
// sharing a single v_rcp between both outputs. Trans ops/step: 4 -> 1.
// Theory: the invariant ~270cyc/step stall across R2/R4b/R6 tracks the
// constant 4 trans/step/SIMD (quarter-rate trans pipe + serial tail).
//   tanh(y) ~ y*(135135+17325u+378u^2+u^3)/(135135+62370u+3150u^2+28u^3),
//   u=y^2, y clamped to +-5; max err ~1.5e-4 (hand-checked at y=2,3,4,5,6).

typedef float f2 __attribute__((ext_vector_type(2)));

#define RNN_B 4096
#define RNN_T 1024
#define RNN_H 32
#define GROUPS 16             // batches per block (16-lane groups)
#define BLOCK 256
#define DEPTH 4               // T-unroll / x prefetch distance

template <int M>
__device__ __forceinline__ f2 rotm(f2 v) {
    // DPP row_ror:M — lane i reads lane (i-M)&15 within its 16-lane row
    f2 r;
    r.x = __int_as_float(__builtin_amdgcn_mov_dpp(__float_as_int(v.x), 0x120 | M, 0xf, 0xf, true));
    r.y = __int_as_float(__builtin_amdgcn_mov_dpp(__float_as_int(v.y), 0x120 | M, 0xf, 0xf, true));
    return r;
}

__global__ __launch_bounds__(BLOCK) void vanilla_rnn_kernel(
    const float* __restrict__ x,     // [B,T,3]
    const float* __restrict__ W_ih,  // [32,3]
    const float* __restrict__ b_ih,  // [32]
    const float* __restrict__ W_hh,  // [32,32]
    const float* __restrict__ b_hh,  // [32]
    const float* __restrict__ W_fc,  // [2,32]
    const float* __restrict__ b_fc,  // [2]
    float* __restrict__ out,         // [B,T,32]
    float* __restrict__ hn_out)      // [B,2]
{
    const int tid = threadIdx.x;
    const int g   = tid >> 4;        // batch group within block
    const int p   = tid & 15;        // pair position within 16-lane row
    const int b   = blockIdx.x * GROUPS + g;
    const int j0  = 2 * p;
    const int j1  = 2 * p + 1;

    __shared__ float hs[GROUPS][32]; // epilogue only

    // W_hh rows j0,j1 in rotation order (pair q=(p-m)&15). No pre-scale.
    f2 Wa[16], Wb[16];
#pragma unroll
    for (int m = 0; m < 16; ++m) {
        const int q = (p - m) & 15;
        Wa[m].x = W_hh[j0 * 32 + 2 * q];
        Wa[m].y = W_hh[j0 * 32 + 2 * q + 1];
        Wb[m].x = W_hh[j1 * 32 + 2 * q];
        Wb[m].y = W_hh[j1 * 32 + 2 * q + 1];
    }

    // x-projection constants (.x -> j0, .y -> j1)
    f2 wi0, wi1, wi2, bs;
    wi0.x = W_ih[j0 * 3 + 0];  wi0.y = W_ih[j1 * 3 + 0];
    wi1.x = W_ih[j0 * 3 + 1];  wi1.y = W_ih[j1 * 3 + 1];
    wi2.x = W_ih[j0 * 3 + 2];  wi2.y = W_ih[j1 * 3 + 2];
    bs.x  = b_ih[j0] + b_hh[j0];
    bs.y  = b_ih[j1] + b_hh[j1];

    const float* xb = x + (size_t)b * RNN_T * 3;
    float*       ob = out + (size_t)b * RNN_T * RNN_H;

    float xs[DEPTH][3];
#pragma unroll
    for (int d = 0; d < DEPTH; ++d)
#pragma unroll
        for (int c = 0; c < 3; ++c) xs[d][c] = xb[d * 3 + c];

    float hj0 = 0.0f, hj1 = 0.0f;

    for (int tb = 0; tb < RNN_T; tb += DEPTH) {
        const int tnb = (tb + DEPTH < RNN_T) ? (tb + DEPTH) : tb;
        float nxs[DEPTH][3];
#pragma unroll
        for (int d = 0; d < DEPTH; ++d)
#pragma unroll
            for (int c = 0; c < 3; ++c) nxs[d][c] = xb[(tnb + d) * 3 + c];

        // x-projection for this block (h-independent)
        f2 xp[DEPTH];
#pragma unroll
        for (int d = 0; d < DEPTH; ++d) {
            f2 v = bs;
            v = __builtin_elementwise_fma(wi0, (f2){xs[d][0], xs[d][0]}, v);
            v = __builtin_elementwise_fma(wi1, (f2){xs[d][1], xs[d][1]}, v);
            v = __builtin_elementwise_fma(wi2, (f2){xs[d][2], xs[d][2]}, v);
            xp[d] = v;
        }

#pragma unroll
        for (int d = 0; d < DEPTH; ++d) {
            f2 hp; hp.x = hj0; hp.y = hj1;

            f2 acc_a, acc_b;
            acc_a.x = xp[d].x; acc_a.y = 0.0f;
            acc_b.x = xp[d].y; acc_b.y = 0.0f;

            acc_a = __builtin_elementwise_fma(hp, Wa[0], acc_a);
            acc_b = __builtin_elementwise_fma(hp, Wb[0], acc_b);
#define ROT_STEP(M)                                               \
            {                                                     \
                const f2 r = rotm<M>(hp);                         \
                acc_a = __builtin_elementwise_fma(r, Wa[M], acc_a);  \
                acc_b = __builtin_elementwise_fma(r, Wb[M], acc_b);  \
            }
            ROT_STEP(1)  ROT_STEP(2)  ROT_STEP(3)  ROT_STEP(4)
            ROT_STEP(5)  ROT_STEP(6)  ROT_STEP(7)  ROT_STEP(8)
            ROT_STEP(9)  ROT_STEP(10) ROT_STEP(11) ROT_STEP(12)
            ROT_STEP(13) ROT_STEP(14) ROT_STEP(15)
#undef ROT_STEP

            f2 yv;
            yv.x = acc_a.x + acc_a.y;   // pre-tanh for j0
            yv.y = acc_b.x + acc_b.y;   // pre-tanh for j1

            // tanh via clamped Pade(7,6); ONE rcp shared by both outputs.
            const f2 yc = __builtin_elementwise_min(
                __builtin_elementwise_max(yv, (f2){-5.0f, -5.0f}),
                (f2){5.0f, 5.0f});
            const f2 u = yc * yc;
            f2 np = u + (f2){378.0f, 378.0f};
            np = __builtin_elementwise_fma(u, np, (f2){17325.0f, 17325.0f});
            np = __builtin_elementwise_fma(u, np, (f2){135135.0f, 135135.0f});
            np = np * yc;                                  // numerators
            f2 dp = __builtin_elementwise_fma(u, (f2){28.0f, 28.0f},
                                              (f2){3150.0f, 3150.0f});
            dp = __builtin_elementwise_fma(u, dp, (f2){62370.0f, 62370.0f});
            dp = __builtin_elementwise_fma(u, dp, (f2){135135.0f, 135135.0f});

            const float r   = __builtin_amdgcn_rcpf(dp.x * dp.y);
            const float tha = np.x * dp.y * r;
            const float thb = np.y * dp.x * r;

            f2 st; st.x = tha; st.y = thb;
            __builtin_nontemporal_store(
                st, reinterpret_cast<f2*>(ob + (size_t)(tb + d) * RNN_H) + p);

            hj0 = tha; hj1 = thb;
        }

#pragma unroll
        for (int d = 0; d < DEPTH; ++d)
#pragma unroll
            for (int c = 0; c < 3; ++c) xs[d][c] = nxs[d][c];
    }

    // h_n = h_T @ W_fc^T + b_fc  (16-lane group is wave-internal, no barrier)
    hs[g][j0] = hj0;
    hs[g][j1] = hj1;
    if (p < 2) {
        float acc = b_fc[p];
#pragma unroll
        for (int k = 0; k < 32; ++k) acc = fmaf(W_fc[p * 32 + k], hs[g][k], acc);
        hn_out[(size_t)b * 2 + p] = acc;
    }
}

extern "C" void kernel_launch(void* const* d_in, const int* in_sizes, int n_in,
                              void* d_out, int out_size, void* d_ws, size_t ws_size,
                              hipStream_t stream) {
    const float* x    = (const float*)d_in[0];
    const float* W_ih = (const float*)d_in[1];
    const float* b_ih = (const float*)d_in[2];
    const float* W_hh = (const float*)d_in[3];
    const float* b_hh = (const float*)d_in[4];
    const float* W_fc = (const float*)d_in[5];
    const float* b_fc = (const float*)d_in[6];

    float* out    = (float*)d_out;                                   // [B,T,H]
    float* hn_out = out + (size_t)RNN_B * RNN_T * RNN_H;             // [B,2]

    const int grid = RNN_B / GROUPS;  // 256 blocks = 1024 waves = 1/SIMD
    vanilla_rnn_kernel<<<grid, BLOCK, 0, stream>>>(
        x, W_ih, b_ih, W_hh, b_hh, W_fc, b_fc, out, hn_out);
}

// Round 11
// 210.798 us; speedup vs baseline: 1.4571x; 1.1002x over previous
//
#include <hip/hip_runtime.h>

// VanillaRNN: B=4096, T=1024, I=3, H=32, O=2
// out[b,t,j] = h_t[j];  h_t = tanh(x_t @ W_ih^T + b_ih + b_hh + h_{t-1} @ W_hh^T)
// h_n[b,o] = h_T @ W_fc^T + b_fc
//
// R10 = R4b math/layout (16 lanes/batch, lane owns j=2p,2p+1, independent
// dpp row_ror:m pair rotations, DEPTH=4, nontemporal f2 stores, 1 wave/SIMD)
// with WAVE-INTERNAL LDS x-staging (R9 intent, race-free):
//  - each wave stages x for its own 4 groups: lanes 0..47 load 1 dword/block
//  - ring: 2 slots/wave + 1 reg per parity; load -> ds_write distance = 2
//    blocks (~1000+cyc), ds_write -> ds_read = 2 blocks (program order,
//    same-wave DS queue => ordered, NO barriers)
//  - x consumed via ds_read (lgkmcnt) -> decoupled from the store vmcnt queue
//  - sched_barrier(0) pins each staging cluster at block start
//  - __launch_bounds__(256,1): regalloc for 1 wave/EU, no sink pressure

typedef float f2 __attribute__((ext_vector_type(2)));

#define RNN_B 4096
#define RNN_T 1024
#define RNN_H 32
#define GROUPS 16             // batches per block (16-lane groups)
#define BLOCK 256
#define DEPTH 4               // steps per staging block
#define NBLK (RNN_T / DEPTH)  // 256

#define SCALE 2.8853900817779268f   // 2*log2(e)

template <int M>
__device__ __forceinline__ f2 rotm(f2 v) {
    // DPP row_ror:M — lane i reads lane (i-M)&15 within its 16-lane row
    f2 r;
    r.x = __int_as_float(__builtin_amdgcn_mov_dpp(__float_as_int(v.x), 0x120 | M, 0xf, 0xf, true));
    r.y = __int_as_float(__builtin_amdgcn_mov_dpp(__float_as_int(v.y), 0x120 | M, 0xf, 0xf, true));
    return r;
}

__global__ __launch_bounds__(BLOCK, 1) void vanilla_rnn_kernel(
    const float* __restrict__ x,     // [B,T,3]
    const float* __restrict__ W_ih,  // [32,3]
    const float* __restrict__ b_ih,  // [32]
    const float* __restrict__ W_hh,  // [32,32]
    const float* __restrict__ b_hh,  // [32]
    const float* __restrict__ W_fc,  // [2,32]
    const float* __restrict__ b_fc,  // [2]
    float* __restrict__ out,         // [B,T,32]
    float* __restrict__ hn_out)      // [B,2]
{
    const int tid = threadIdx.x;
    const int g   = tid >> 4;          // group within block (0..15)
    const int p   = tid & 15;          // pair position within 16-lane row
    const int wv  = tid >> 6;          // wave within block (0..3)
    const int gw  = (tid >> 4) & 3;    // group within wave (0..3)
    const int b   = blockIdx.x * GROUPS + g;
    const int j0  = 2 * p;
    const int j1  = 2 * p + 1;

    __shared__ float hs[GROUPS][32];                  // epilogue only
    __shared__ __align__(16) float xs4[4][2][4][12];  // [wave][slot][gw][12]

    // loader role: lanes 0..47 of each wave stream 1 dword per block
    const int  lw     = tid & 63;
    const bool loader = lw < 48;
    const int  lg     = lw / 12;       // group-in-wave it loads for
    const int  fr     = lw % 12;       // float index within a 12-float block
    const float* lsrc = x + (size_t)(blockIdx.x * GROUPS + wv * 4 + lg) * (RNN_T * 3) + fr;

    // W_hh rows j0,j1 in rotation order (pair q=(p-m)&15), pre-scaled.
    f2 Wa[16], Wb[16];
#pragma unroll
    for (int m = 0; m < 16; ++m) {
        const int q = (p - m) & 15;
        Wa[m].x = W_hh[j0 * 32 + 2 * q]     * SCALE;
        Wa[m].y = W_hh[j0 * 32 + 2 * q + 1] * SCALE;
        Wb[m].x = W_hh[j1 * 32 + 2 * q]     * SCALE;
        Wb[m].y = W_hh[j1 * 32 + 2 * q + 1] * SCALE;
    }

    // x-projection constants (.x -> j0, .y -> j1), pre-scaled
    f2 wi0, wi1, wi2, bs;
    wi0.x = W_ih[j0 * 3 + 0] * SCALE;  wi0.y = W_ih[j1 * 3 + 0] * SCALE;
    wi1.x = W_ih[j0 * 3 + 1] * SCALE;  wi1.y = W_ih[j1 * 3 + 1] * SCALE;
    wi2.x = W_ih[j0 * 3 + 2] * SCALE;  wi2.y = W_ih[j1 * 3 + 2] * SCALE;
    bs.x  = (b_ih[j0] + b_hh[j0]) * SCALE;
    bs.y  = (b_ih[j1] + b_hh[j1]) * SCALE;

    float* ob = out + (size_t)b * RNN_T * RNN_H;

    // prologue: slots <- blocks 0,1; regs <- blocks 2,3 (all wave-internal)
    float xregA = 0.0f, xregB = 0.0f;
    if (loader) {
        const float d0 = lsrc[0];
        const float d1 = lsrc[12];
        xregA = lsrc[24];
        xregB = lsrc[36];
        xs4[wv][0][lg][fr] = d0;
        xs4[wv][1][lg][fr] = d1;
    }

    float hj0 = 0.0f, hj1 = 0.0f;

#define BLOCK_BODY(SLOT, XREG, KB)                                            \
    {                                                                         \
        const float4* sp = reinterpret_cast<const float4*>(&xs4[wv][SLOT][gw][0]); \
        const float4 xq0 = sp[0];                                             \
        const float4 xq1 = sp[1];                                             \
        const float4 xq2 = sp[2];                                             \
        if (loader) {                                                         \
            xs4[wv][SLOT][lg][fr] = XREG;          /* data for KB+2 */        \
            const int kf = ((KB) + 4 < NBLK) ? (KB) + 4 : NBLK - 1;           \
            XREG = lsrc[(size_t)kf * 12];          /* data for KB+4 */        \
        }                                                                     \
        __builtin_amdgcn_sched_barrier(0);                                    \
        const float xv[12] = {xq0.x, xq0.y, xq0.z, xq0.w,                     \
                              xq1.x, xq1.y, xq1.z, xq1.w,                     \
                              xq2.x, xq2.y, xq2.z, xq2.w};                    \
        _Pragma("unroll")                                                     \
        for (int d = 0; d < DEPTH; ++d) {                                     \
            f2 hp; hp.x = hj0; hp.y = hj1;                                    \
            f2 acc_a = {0.0f, 0.0f}, acc_b = {0.0f, 0.0f};                    \
            acc_a = __builtin_elementwise_fma(hp, Wa[0], acc_a);              \
            acc_b = __builtin_elementwise_fma(hp, Wb[0], acc_b);              \
            ROT_STEP(1)  ROT_STEP(2)  ROT_STEP(3)  ROT_STEP(4)                \
            ROT_STEP(5)  ROT_STEP(6)  ROT_STEP(7)  ROT_STEP(8)                \
            ROT_STEP(9)  ROT_STEP(10) ROT_STEP(11) ROT_STEP(12)               \
            ROT_STEP(13) ROT_STEP(14) ROT_STEP(15)                            \
            f2 xpv = bs;                                                      \
            xpv = __builtin_elementwise_fma(wi0, (f2){xv[d*3+0], xv[d*3+0]}, xpv); \
            xpv = __builtin_elementwise_fma(wi1, (f2){xv[d*3+1], xv[d*3+1]}, xpv); \
            xpv = __builtin_elementwise_fma(wi2, (f2){xv[d*3+2], xv[d*3+2]}, xpv); \
            const float ya = acc_a.x + acc_a.y + xpv.x;                       \
            const float yb = acc_b.x + acc_b.y + xpv.y;                       \
            const float tha = fmaf(-2.0f, __builtin_amdgcn_rcpf(exp2f(ya) + 1.0f), 1.0f); \
            const float thb = fmaf(-2.0f, __builtin_amdgcn_rcpf(exp2f(yb) + 1.0f), 1.0f); \
            f2 st; st.x = tha; st.y = thb;                                    \
            __builtin_nontemporal_store(                                      \
                st, reinterpret_cast<f2*>(ob + (size_t)((KB) * DEPTH + d) * RNN_H) + p); \
            hj0 = tha; hj1 = thb;                                             \
        }                                                                     \
    }

#define ROT_STEP(M)                                               \
            {                                                     \
                const f2 r = rotm<M>(hp);                         \
                acc_a = __builtin_elementwise_fma(r, Wa[M], acc_a);  \
                acc_b = __builtin_elementwise_fma(r, Wb[M], acc_b);  \
            }

    for (int k = 0; k < NBLK; k += 2) {
        BLOCK_BODY(0, xregA, k)
        BLOCK_BODY(1, xregB, k + 1)
    }

#undef ROT_STEP
#undef BLOCK_BODY

    // h_n = h_T @ W_fc^T + b_fc  (16-lane group is wave-internal, no barrier)
    hs[g][j0] = hj0;
    hs[g][j1] = hj1;
    if (p < 2) {
        float acc = b_fc[p];
#pragma unroll
        for (int k = 0; k < 32; ++k) acc = fmaf(W_fc[p * 32 + k], hs[g][k], acc);
        hn_out[(size_t)b * 2 + p] = acc;
    }
}

extern "C" void kernel_launch(void* const* d_in, const int* in_sizes, int n_in,
                              void* d_out, int out_size, void* d_ws, size_t ws_size,
                              hipStream_t stream) {
    const float* x    = (const float*)d_in[0];
    const float* W_ih = (const float*)d_in[1];
    const float* b_ih = (const float*)d_in[2];
    const float* W_hh = (const float*)d_in[3];
    const float* b_hh = (const float*)d_in[4];
    const float* W_fc = (const float*)d_in[5];
    const float* b_fc = (const float*)d_in[6];

    float* out    = (float*)d_out;                                   // [B,T,H]
    float* hn_out = out + (size_t)RNN_B * RNN_T * RNN_H;             // [B,2]

    const int grid = RNN_B / GROUPS;  // 256 blocks = 1024 waves = 1/SIMD
    vanilla_rnn_kernel<<<grid, BLOCK, 0, stream>>>(
        x, W_ih, b_ih, W_hh, b_hh, W_fc, b_fc, out, hn_out);
}